// Round 1
// 400.721 us; speedup vs baseline: 1.0163x; 1.0163x over previous
//
#include <hip/hip_runtime.h>

// Problem constants (fixed by the reference)
#define H_DIM   1024
#define G_DIM   128
#define N_DIM   384            // 3*G
#define M_TOTAL 65536          // 32*2048 rows
#define BM      64             // rows per block
#define NSTEP   32             // K-steps of BK=32
#define BUF_FLOATS 2048        // one LDS x-buffer: 64 rows x 32 fp32 = 8 KB

typedef _Float16 half8  __attribute__((ext_vector_type(8)));
typedef __fp16   fp16x2 __attribute__((ext_vector_type(2)));
typedef float    f32x4  __attribute__((ext_vector_type(4)));

__device__ __forceinline__ float fast_sigmoid(float v) {
    return 1.0f / (1.0f + __expf(-v));
}
__device__ __forceinline__ float fast_tanh(float v) {
    return 1.0f - 2.0f / (__expf(2.0f * v) + 1.0f);
}

__device__ __forceinline__ half8 cvt8(f32x4 a, f32x4 b) {
    fp16x2 p0 = __builtin_amdgcn_cvt_pkrtz(a[0], a[1]);
    fp16x2 p1 = __builtin_amdgcn_cvt_pkrtz(a[2], a[3]);
    fp16x2 p2 = __builtin_amdgcn_cvt_pkrtz(b[0], b[1]);
    fp16x2 p3 = __builtin_amdgcn_cvt_pkrtz(b[2], b[3]);
    half8 h;
    h[0] = (_Float16)p0[0]; h[1] = (_Float16)p0[1];
    h[2] = (_Float16)p1[0]; h[3] = (_Float16)p1[1];
    h[4] = (_Float16)p2[0]; h[5] = (_Float16)p2[1];
    h[6] = (_Float16)p3[0]; h[7] = (_Float16)p3[1];
    return h;
}

// weight_ih (384x1024 fp32 row-major = B^T, K contiguous) -> f16 fragments,
// fragment-linear: frag id f = ct*32 + ktg (ktg = 32-wide K group), layout
// wf[f*512 + lane*8]: lane holds B^T[col=ct*16+(lane&15)][k=ktg*32+(lane>>4)*8 ..+8]
__global__ __launch_bounds__(256) void prep_w_kernel(const float* __restrict__ w,
                                                     _Float16* __restrict__ wf) {
    int gid  = blockIdx.x * 256 + threadIdx.x;   // 0 .. 49151
    int lane = gid & 63;
    int fid  = gid >> 6;
    int ktg  = fid & 31;
    int ct   = fid >> 5;
    int col  = ct * 16 + (lane & 15);
    int kb   = ktg * 32 + (lane >> 4) * 8;
    const f32x4* src = (const f32x4*)(w + (size_t)col * H_DIM + kb);
    f32x4 v0 = src[0], v1 = src[1];
    half8 h;
    #pragma unroll
    for (int j = 0; j < 4; ++j) { h[j] = (_Float16)v0[j]; h[4 + j] = (_Float16)v1[j]; }
    *(half8*)(wf + (size_t)gid * 8) = h;
}

// ---- raw barrier / waitcnt (NO vmcnt(0) drain like __syncthreads) ----
#define FENCE() asm volatile("" ::: "memory")
// gfx9 waitcnt imm: vmcnt[3:0], expcnt[6:4]=7 (nowait), lgkmcnt[11:8]=15 (nowait)
#define WAITV(N) { FENCE(); __builtin_amdgcn_s_waitcnt(0x0F70 | (N)); FENCE(); }
#define BARR()   { FENCE(); __builtin_amdgcn_s_barrier(); FENCE(); }

__global__ __launch_bounds__(512, 4) void ping_main_kernel(
    const float* __restrict__ x, const _Float16* __restrict__ wf,
    const float* __restrict__ bias_ih, const float* __restrict__ bias_hh,
    const float* __restrict__ lin_w, const float* __restrict__ lin_b,
    float* __restrict__ out)
{
    __shared__ float shX[4 * BUF_FLOATS];   // 32 KB: 4 buffers of 64x32 fp32
    __shared__ float sh_out[BM];

    const int t    = threadIdx.x;       // 0..511
    const int lane = t & 63;
    const int wv   = t >> 6;            // wave 0..7
    const int ln   = lane & 15;
    const int quad = lane >> 4;

    if (t < BM) sh_out[t] = 0.0f;

    const size_t row0 = (size_t)blockIdx.x * BM;

    // --- DMA source mapping (1 global_load_lds of 16B per thread per step) ---
    // wave wv stages rows 8wv..8wv+7; lane l -> row 8wv + l/8, LDS chunk l%8.
    // XOR pair-swizzle on SOURCE chunk so LDS rows aren't bank-aliased:
    // LDS (r, c) holds global chunk c ^ (2*(r&3)).
    const int drow = wv * 8 + (lane >> 3);                 // 0..63
    const int cg   = (lane & 7) ^ (2 * ((lane >> 3) & 3)); // source chunk
    const float* xsrc = x + (row0 + drow) * (size_t)H_DIM + cg * 4;
    float* ldsSeg = &shX[wv * 256];     // wave-uniform base within buffer 0

#define DMA_ISSUE(K) \
    __builtin_amdgcn_global_load_lds( \
        (const __attribute__((address_space(1))) void*)(xsrc + (size_t)(K) * 32), \
        (__attribute__((address_space(3))) void*)(ldsSeg + ((K) & 3) * BUF_FLOATS), \
        16, 0, 0)

    // --- A fragment read addresses (even chunk of the pair; odd at +16B) ---
    const char* aAddr[4];
    #pragma unroll
    for (int rt = 0; rt < 4; ++rt) {
        int r  = rt * 16 + ln;
        int ce = (2 * quad) ^ (2 * (ln & 3));   // swizzled even chunk
        aAddr[rt] = (const char*)&shX[0] + r * 128 + ce * 16;
    }

    // --- B fragment pointers: wave wv owns ct in {wv, wv+8, wv+16} so the
    // (r,z,n) triple for gate column g = 16*wv + ln stays lane-local. ---
    const _Float16* pb[3];
    #pragma unroll
    for (int i = 0; i < 3; ++i)
        pb[i] = wf + (size_t)((wv + 8 * i) * 32) * 512 + lane * 8;

    f32x4 acc[3][4];
    #pragma unroll
    for (int i = 0; i < 3; ++i)
        #pragma unroll
        for (int rt = 0; rt < 4; ++rt)
            acc[i][rt] = (f32x4){0.f, 0.f, 0.f, 0.f};

    // --- Register double-buffer for the wf fragments, prefetched TWO K-steps
    // ahead. Parity trick: step k and k+2 share (k&1), and within a step the
    // consume (MFMA) happens before the overwrite (next-next prefetch), so two
    // slots suffice. All indices are compile-time constants (no scratch). ---
    half8 bf[2][3];

    // prologue: 3 x-DMA steps in flight, wf fragments for steps 0 and 1.
    // vmcnt issue order: D0 D1 D2 b0x3 b1x3  -> 8 entries after D0.
    DMA_ISSUE(0); DMA_ISSUE(1); DMA_ISSUE(2);
    #pragma unroll
    for (int i = 0; i < 3; ++i) {
        bf[0][i] = *(const half8*)(pb[i]);           // bfr(0)
        bf[1][i] = *(const half8*)(pb[i] + 512);     // bfr(1)
    }

    // Steady-state queue per step k: [.., D(k+1), b(k)x3, D(k+2), b(k+1)x3]
    //  => exactly 8 vmem entries after D(k). WAITV(8) retires D(k) (x tile k
    // landed in LDS) without ever draining a freshly-issued DMA or b-load.
    // The compiler's own wait for bf consumption lands at vmcnt(>=6).
#define ITER_BODY(KB, BUFI, WAITN, DO_ISSUE, DO_BLOAD) { \
    WAITV(WAITN); \
    BARR(); \
    if (DO_ISSUE) { DMA_ISSUE((KB) + 3); } \
    _Pragma("unroll") \
    for (int rt = 0; rt < 4; ++rt) { \
        f32x4 ve = *(const f32x4*)(aAddr[rt] + (BUFI) * 8192); \
        f32x4 vo = *(const f32x4*)(aAddr[rt] + (BUFI) * 8192 + 16); \
        half8 afr = cvt8(ve, vo); \
        _Pragma("unroll") \
        for (int i = 0; i < 3; ++i) \
            acc[i][rt] = __builtin_amdgcn_mfma_f32_16x16x32_f16(afr, bf[(BUFI) & 1][i], acc[i][rt], 0, 0, 0); \
    } \
    if (DO_BLOAD) { \
        _Pragma("unroll") \
        for (int i = 0; i < 3; ++i) \
            bf[(BUFI) & 1][i] = *(const half8*)(pb[i] + (size_t)((KB) + 2) * 512); \
    } }

    for (int kb = 0; kb < 28; kb += 4) {
        ITER_BODY(kb + 0, 0, 8, true, true);
        ITER_BODY(kb + 1, 1, 8, true, true);
        ITER_BODY(kb + 2, 2, 8, true, true);
        ITER_BODY(kb + 3, 3, 8, true, true);
    }
    ITER_BODY(28, 0, 8, true,  true);    // issues D31 (last), prefetches b30
    ITER_BODY(29, 1, 8, false, true);    // prefetches b31
    ITER_BODY(30, 2, 4, false, false);   // exact bound 7; 4 is safe (tail)
    ITER_BODY(31, 3, 0, false, false);   // exact bound 6; 0 is safe (tail)

    // --- Epilogue: gate column g = 16*wv + ln; acc[0]=r, acc[1]=z, acc[2]=n ---
    const int g = 16 * wv + ln;
    const float b_ir = bias_ih[g];
    const float b_iz = bias_ih[G_DIM + g];
    const float b_in = bias_ih[2 * G_DIM + g];
    const float b_hr = bias_hh[g];
    const float b_hz = bias_hh[G_DIM + g];
    const float b_hn = bias_hh[2 * G_DIM + g];
    const float lw   = lin_w[g];

    #pragma unroll
    for (int rt = 0; rt < 4; ++rt) {
        #pragma unroll
        for (int reg = 0; reg < 4; ++reg) {
            const float r = fast_sigmoid(acc[0][rt][reg] + b_ir + b_hr);
            const float z = fast_sigmoid(acc[1][rt][reg] + b_iz + b_hz);
            const float n = fast_tanh(acc[2][rt][reg] + b_in + r * b_hn);
            float v = lw * (1.0f - z) * n;
            // reduce over the 16 gate columns held by this quad-row group
            v += __shfl_xor(v, 1);
            v += __shfl_xor(v, 2);
            v += __shfl_xor(v, 4);
            v += __shfl_xor(v, 8);
            if (ln == 0) atomicAdd(&sh_out[rt * 16 + quad * 4 + reg], v);
        }
    }

    __syncthreads();
    if (t < BM) out[row0 + t] = sh_out[t] + lin_b[0];
}

extern "C" void kernel_launch(void* const* d_in, const int* in_sizes, int n_in,
                              void* d_out, int out_size, void* d_ws, size_t ws_size,
                              hipStream_t stream) {
    const float* x      = (const float*)d_in[0];
    const float* w_ih   = (const float*)d_in[1];
    // d_in[2] = weight_hh: unused (hidden state is always zero in the reference)
    const float* b_ih   = (const float*)d_in[3];
    const float* b_hh   = (const float*)d_in[4];
    const float* lin_w  = (const float*)d_in[5];
    const float* lin_b  = (const float*)d_in[6];
    float* out          = (float*)d_out;
    _Float16* wf        = (_Float16*)d_ws;   // 384*1024*2 = 768 KB scratch

    hipLaunchKernelGGL(prep_w_kernel, dim3((N_DIM / 16) * 32 * 64 / 256), dim3(256), 0, stream,
                       w_ih, wf);
    hipLaunchKernelGGL(ping_main_kernel, dim3(M_TOTAL / BM), dim3(512), 0, stream,
                       x, wf, b_ih, b_hh, lin_w, lin_b, out);
}